// Round 1
// baseline (101212.689 us; speedup 1.0000x reference)
//
#include <hip/hip_runtime.h>
#include <hip/hip_bf16.h>

#define SEQ 4096
#define EMB 1024
#define HID 2048
#define G4  8192
#define NL  256

typedef __attribute__((ext_vector_type(8))) short bf16x8;
typedef __attribute__((ext_vector_type(4))) float f32x4;

static __device__ __forceinline__ unsigned short f2bf(float f) {
    unsigned int x = __builtin_bit_cast(unsigned int, f);
    return (unsigned short)((x + 0x7FFFu + ((x >> 16) & 1u)) >> 16);
}
static __device__ __forceinline__ float lo16(unsigned int u) {
    return __builtin_bit_cast(float, u << 16);
}
static __device__ __forceinline__ float hi16(unsigned int u) {
    return __builtin_bit_cast(float, u & 0xFFFF0000u);
}
static __device__ __forceinline__ float bf2f(unsigned short u) {
    return __builtin_bit_cast(float, ((unsigned int)u) << 16);
}

// ---------------- fp32 -> bf16 convert ----------------
__global__ __launch_bounds__(256) void k_f2b(const float* __restrict__ in,
                                             unsigned short* __restrict__ out, int n) {
    int i = (blockIdx.x * 256 + threadIdx.x) * 4;
    if (i < n) {
        float4 v = *(const float4*)&in[i];
        ushort4 u;
        u.x = f2bf(v.x); u.y = f2bf(v.y); u.z = f2bf(v.z); u.w = f2bf(v.w);
        *(ushort4*)&out[i] = u;
    }
}

// ---------------- embedding gather + cast ----------------
__global__ __launch_bounds__(256) void k_emb(const int* __restrict__ ids,
                                             const float* __restrict__ W_emb,
                                             unsigned short* __restrict__ out) {
    int t = blockIdx.x;
    int e0 = threadIdx.x * 4;
    const float4 v = *(const float4*)&W_emb[(size_t)ids[t] * EMB + e0];
    ushort4 u;
    u.x = f2bf(v.x); u.y = f2bf(v.y); u.z = f2bf(v.z); u.w = f2bf(v.w);
    *(ushort4*)&out[(size_t)t * EMB + e0] = u;
}

// ---------------- bf16 MFMA GEMM:  C[M,N] = A[M,K] * B[N,K]^T + bias ----------------
#define BM 128
#define BN 128
#define BK 32
__global__ __launch_bounds__(256) void k_gemm_bt(
    const unsigned short* __restrict__ A, const unsigned short* __restrict__ B,
    const float* __restrict__ bias1, const float* __restrict__ bias2,
    float* __restrict__ Cf, unsigned short* __restrict__ Cb,
    int M, int N, int K)
{
    __shared__ unsigned short As[BM * BK];
    __shared__ unsigned short Bs[BN * BK];
    const int bm = blockIdx.x * BM;
    const int bn = blockIdx.y * BN;
    const int tid = threadIdx.x;
    const int wave = tid >> 6, lane = tid & 63;
    const int wm = (wave & 1) * 64, wn = (wave >> 1) * 64;
    const int row16 = lane & 15, quad = lane >> 4;

    f32x4 acc[4][4];
#pragma unroll
    for (int i = 0; i < 4; ++i)
#pragma unroll
        for (int j = 0; j < 4; ++j) acc[i][j] = (f32x4){0.f, 0.f, 0.f, 0.f};

    for (int k0 = 0; k0 < K; k0 += BK) {
        __syncthreads();
#pragma unroll
        for (int s = 0; s < 2; ++s) {
            int c = tid + s * 256;
            int r = c >> 2, col = (c & 3) * 8;
            *(uint4*)&As[r * BK + col] = *(const uint4*)&A[(size_t)(bm + r) * K + k0 + col];
            *(uint4*)&Bs[r * BK + col] = *(const uint4*)&B[(size_t)(bn + r) * K + k0 + col];
        }
        __syncthreads();
        bf16x8 af[4], bfr[4];
#pragma unroll
        for (int i = 0; i < 4; ++i) {
            af[i]  = *(const bf16x8*)&As[(wm + i * 16 + row16) * BK + quad * 8];
            bfr[i] = *(const bf16x8*)&Bs[(wn + i * 16 + row16) * BK + quad * 8];
        }
#pragma unroll
        for (int i = 0; i < 4; ++i)
#pragma unroll
            for (int j = 0; j < 4; ++j)
                acc[i][j] = __builtin_amdgcn_mfma_f32_16x16x32_bf16(af[i], bfr[j], acc[i][j], 0, 0, 0);
    }

#pragma unroll
    for (int j = 0; j < 4; ++j) {
        int col = bn + wn + j * 16 + row16;
        float bsum = (bias1 ? bias1[col] : 0.f) + (bias2 ? bias2[col] : 0.f);
#pragma unroll
        for (int i = 0; i < 4; ++i) {
#pragma unroll
            for (int r = 0; r < 4; ++r) {
                int row = bm + wm + i * 16 + quad * 4 + r;
                float v = acc[i][j][r] + bsum;
                if (Cf) Cf[(size_t)row * N + col] = v;
                else    Cb[(size_t)row * N + col] = f2bf(v);
            }
        }
    }
}

// ---------------- persistent LSTM recurrence ----------------
// 256 blocks x 1024 threads. Block b owns h-indices [b*8, b*8+8) and the 32 gate
// rows {q*2048 + b*8 + jj}. W_hh rows live in LDS as bf16 (128KB) for all steps.
// LDS ~139KB -> exactly 1 block/CU -> all 256 blocks co-resident.
#define LSTM_LDS (32 * 2048 * 2 + 2048 * 4 + (32 + 32 + 8) * 4)
__global__ __launch_bounds__(1024, 1) void k_lstm(
    const float* __restrict__ W_hh,          // [8192,2048] fp32
    const unsigned short* __restrict__ xg,   // [4096,8192] bf16
    const float* __restrict__ h0, const float* __restrict__ c0,
    float* __restrict__ hs,                  // [4096,2048] fp32
    unsigned short* __restrict__ hsb,        // [4096,2048] bf16
    float* __restrict__ outHC,               // d_out + SEQ*NL : [hL(2048), cL(2048)]
    unsigned int* __restrict__ flags)        // [4096*256]
{
    extern __shared__ char smem[];
    unsigned short* Wl = (unsigned short*)smem;            // 32*2048 bf16
    float* hl   = (float*)(smem + 32 * 2048 * 2);          // 2048
    float* gsum = hl + 2048;                               // 32
    float* gxg  = gsum + 32;                               // 32
    float* cst  = gxg + 32;                                // 8

    const int b = blockIdx.x, tid = threadIdx.x;
    const int wave = tid >> 6, lane = tid & 63;

    // stage this block's 32 W_hh rows into LDS as bf16 (row r_local = q*8+jj)
    for (int i = tid; i < 32 * 2048 / 4; i += 1024) {
        int r = i >> 9;                 // local row
        int cc = (i & 511) << 2;        // col
        int grow = ((r >> 3) << 11) + b * 8 + (r & 7);
        float4 v = *(const float4*)&W_hh[(size_t)grow * 2048 + cc];
        ushort4 u;
        u.x = f2bf(v.x); u.y = f2bf(v.y); u.z = f2bf(v.z); u.w = f2bf(v.w);
        *(ushort4*)&Wl[r * 2048 + cc] = u;
    }
    if (tid < 8) cst[tid] = c0[b * 8 + tid];
    __syncthreads();

    for (int t = 0; t < SEQ; ++t) {
        // prefetch this block's 32 x_gate values (independent of the flag wait)
        float xgv = 0.f;
        if (tid < 32) {
            int grow = ((tid >> 3) << 11) + b * 8 + (tid & 7);
            xgv = bf2f(xg[(size_t)t * G4 + grow]);
        }
        const float* hsrc;
        if (t == 0) {
            hsrc = h0;
        } else {
            if (tid < 256) {
                while (__hip_atomic_load(&flags[(size_t)(t - 1) * 256 + tid],
                                         __ATOMIC_ACQUIRE, __HIP_MEMORY_SCOPE_AGENT) == 0u) {
                    __builtin_amdgcn_s_sleep(1);
                }
            }
            __syncthreads();   // nobody reads h until all 256 producer flags observed
            hsrc = hs + (size_t)(t - 1) * HID;
        }
        for (int i = tid; i < 512; i += 1024)
            *(float4*)&hl[i << 2] = *(const float4*)&hsrc[i << 2];
        if (tid < 32) gxg[tid] = xgv;
        __syncthreads();

        // matvec: wave w -> local rows 2w, 2w+1 ; lane covers 8 cols per pass
        const int r0 = wave * 2;
        const unsigned short* w0 = Wl + r0 * 2048;
        const unsigned short* w1 = Wl + (r0 + 1) * 2048;
        float s0 = 0.f, s1 = 0.f;
#pragma unroll
        for (int p = 0; p < 4; ++p) {
            int base = p * 512 + lane * 8;
            float4 ha = *(const float4*)&hl[base];
            float4 hb = *(const float4*)&hl[base + 4];
            uint4 wa = *(const uint4*)(w0 + base);
            uint4 wb = *(const uint4*)(w1 + base);
            s0 += lo16(wa.x) * ha.x + hi16(wa.x) * ha.y;
            s0 += lo16(wa.y) * ha.z + hi16(wa.y) * ha.w;
            s0 += lo16(wa.z) * hb.x + hi16(wa.z) * hb.y;
            s0 += lo16(wa.w) * hb.z + hi16(wa.w) * hb.w;
            s1 += lo16(wb.x) * ha.x + hi16(wb.x) * ha.y;
            s1 += lo16(wb.y) * ha.z + hi16(wb.y) * ha.w;
            s1 += lo16(wb.z) * hb.x + hi16(wb.z) * hb.y;
            s1 += lo16(wb.w) * hb.z + hi16(wb.w) * hb.w;
        }
#pragma unroll
        for (int off = 32; off > 0; off >>= 1) {
            s0 += __shfl_down(s0, off);
            s1 += __shfl_down(s1, off);
        }
        if (lane == 0) { gsum[r0] = s0; gsum[r0 + 1] = s1; }
        __syncthreads();

        if (tid < 8) {
            float gi = gsum[0 * 8 + tid] + gxg[0 * 8 + tid];
            float gf = gsum[1 * 8 + tid] + gxg[1 * 8 + tid];
            float gg = gsum[2 * 8 + tid] + gxg[2 * 8 + tid];
            float go = gsum[3 * 8 + tid] + gxg[3 * 8 + tid];
            float i_ = 1.f / (1.f + __expf(-gi));
            float f_ = 1.f / (1.f + __expf(-gf));
            float g_ = tanhf(gg);
            float o_ = 1.f / (1.f + __expf(-go));
            float cn = f_ * cst[tid] + i_ * g_;
            float hn = o_ * tanhf(cn);
            cst[tid] = cn;
            hs [(size_t)t * HID + b * 8 + tid] = hn;
            hsb[(size_t)t * HID + b * 8 + tid] = f2bf(hn);
            if (t == SEQ - 1) {
                outHC[b * 8 + tid] = hn;
                outHC[HID + b * 8 + tid] = cn;
            }
        }
        __syncthreads();
        if (tid == 0) {
            __threadfence();  // device-scope release of this step's h writes
            __hip_atomic_store(&flags[(size_t)t * 256 + b], 1u,
                               __ATOMIC_RELEASE, __HIP_MEMORY_SCOPE_AGENT);
        }
    }
}

// ---------------- relu + log_softmax over rows of 256 ----------------
__global__ __launch_bounds__(256) void k_softmax(const float* __restrict__ logits,
                                                 float* __restrict__ out) {
    int row = blockIdx.x * 4 + (threadIdx.x >> 6);
    int lane = threadIdx.x & 63;
    const float* Lr = logits + (size_t)row * NL;
    float4 v = *(const float4*)&Lr[lane * 4];
    v.x = fmaxf(v.x, 0.f); v.y = fmaxf(v.y, 0.f);
    v.z = fmaxf(v.z, 0.f); v.w = fmaxf(v.w, 0.f);
    float m = fmaxf(fmaxf(v.x, v.y), fmaxf(v.z, v.w));
#pragma unroll
    for (int off = 32; off > 0; off >>= 1) m = fmaxf(m, __shfl_xor(m, off));
    float e = __expf(v.x - m) + __expf(v.y - m) + __expf(v.z - m) + __expf(v.w - m);
#pragma unroll
    for (int off = 32; off > 0; off >>= 1) e += __shfl_xor(e, off);
    float ls = __logf(e) + m;
    float4 o;
    o.x = v.x - ls; o.y = v.y - ls; o.z = v.z - ls; o.w = v.w - ls;
    *(float4*)&out[(size_t)row * NL + lane * 4] = o;
}

extern "C" void kernel_launch(void* const* d_in, const int* in_sizes, int n_in,
                              void* d_out, int out_size, void* d_ws, size_t ws_size,
                              hipStream_t stream) {
    const int*   ids   = (const int*)d_in[0];
    const float* h0    = (const float*)d_in[1];
    const float* c0    = (const float*)d_in[2];
    const float* W_emb = (const float*)d_in[3];
    const float* W_ih  = (const float*)d_in[4];
    const float* W_hh  = (const float*)d_in[5];
    const float* b_ih  = (const float*)d_in[6];
    const float* b_hh  = (const float*)d_in[7];
    const float* W_out = (const float*)d_in[8];
    const float* b_out = (const float*)d_in[9];
    float* out = (float*)d_out;

    char* ws = (char*)d_ws;
    unsigned short* xg    = (unsigned short*)(ws);                 // 64MB  [4096,8192] bf16
    float*          hs    = (float*)(ws + 67108864);               // 32MB  [4096,2048] fp32
    unsigned short* hsb   = (unsigned short*)(ws + 100663296);     // 16MB  bf16
    unsigned short* Wihb  = (unsigned short*)(ws + 117440512);     // 16MB
    unsigned short* embb  = (unsigned short*)(ws + 134217728);     // 8MB
    unsigned short* Woutb = (unsigned short*)(ws + 142606336);     // 1MB
    float*          logit = (float*)(ws + 143654912);              // 4MB
    unsigned int*   flags = (unsigned int*)(ws + 147849216);       // 4MB

    hipMemsetAsync(flags, 0, (size_t)SEQ * 256 * 4, stream);

    k_f2b<<<(G4 * EMB / 4 + 255) / 256, 256, 0, stream>>>(W_ih, Wihb, G4 * EMB);
    k_f2b<<<(NL * HID / 4 + 255) / 256, 256, 0, stream>>>(W_out, Woutb, NL * HID);
    k_emb<<<SEQ, 256, 0, stream>>>(ids, W_emb, embb);

    dim3 g1(SEQ / BM, G4 / BN);
    k_gemm_bt<<<g1, 256, 0, stream>>>(embb, Wihb, b_ih, b_hh, nullptr, xg, SEQ, G4, EMB);

    hipFuncSetAttribute((const void*)k_lstm, hipFuncAttributeMaxDynamicSharedMemorySize, LSTM_LDS);
    k_lstm<<<256, 1024, LSTM_LDS, stream>>>(W_hh, xg, h0, c0, hs, hsb, out + (size_t)SEQ * NL, flags);

    dim3 g2(SEQ / BM, NL / BN);
    k_gemm_bt<<<g2, 256, 0, stream>>>(hsb, Woutb, b_out, nullptr, logit, nullptr, SEQ, NL, HID);

    k_softmax<<<SEQ / 4, 256, 0, stream>>>(logit, out);
}

// Round 2
// 19079.962 us; speedup vs baseline: 5.3047x; 5.3047x over previous
//
#include <hip/hip_runtime.h>
#include <hip/hip_bf16.h>

#define SEQ 4096
#define EMB 1024
#define HID 2048
#define G4  8192
#define NL  256

typedef __attribute__((ext_vector_type(8))) short bf16x8;
typedef __attribute__((ext_vector_type(4))) float f32x4;

static __device__ __forceinline__ unsigned short f2bf(float f) {
    unsigned int x = __builtin_bit_cast(unsigned int, f);
    return (unsigned short)((x + 0x7FFFu + ((x >> 16) & 1u)) >> 16);
}
static __device__ __forceinline__ float lo16(unsigned int u) {
    return __builtin_bit_cast(float, u << 16);
}
static __device__ __forceinline__ float hi16(unsigned int u) {
    return __builtin_bit_cast(float, u & 0xFFFF0000u);
}
static __device__ __forceinline__ float bf2f(unsigned short u) {
    return __builtin_bit_cast(float, ((unsigned int)u) << 16);
}

// ---------------- fp32 -> bf16 convert ----------------
__global__ __launch_bounds__(256) void k_f2b(const float* __restrict__ in,
                                             unsigned short* __restrict__ out, int n) {
    int i = (blockIdx.x * 256 + threadIdx.x) * 4;
    if (i < n) {
        float4 v = *(const float4*)&in[i];
        ushort4 u;
        u.x = f2bf(v.x); u.y = f2bf(v.y); u.z = f2bf(v.z); u.w = f2bf(v.w);
        *(ushort4*)&out[i] = u;
    }
}

// ---------------- embedding gather + cast ----------------
__global__ __launch_bounds__(256) void k_emb(const int* __restrict__ ids,
                                             const float* __restrict__ W_emb,
                                             unsigned short* __restrict__ out) {
    int t = blockIdx.x;
    int e0 = threadIdx.x * 4;
    const float4 v = *(const float4*)&W_emb[(size_t)ids[t] * EMB + e0];
    ushort4 u;
    u.x = f2bf(v.x); u.y = f2bf(v.y); u.z = f2bf(v.z); u.w = f2bf(v.w);
    *(ushort4*)&out[(size_t)t * EMB + e0] = u;
}

// ---------------- bf16 MFMA GEMM:  C[M,N] = A[M,K] * B[N,K]^T + bias ----------------
#define BM 128
#define BN 128
#define BK 32
__global__ __launch_bounds__(256) void k_gemm_bt(
    const unsigned short* __restrict__ A, const unsigned short* __restrict__ B,
    const float* __restrict__ bias1, const float* __restrict__ bias2,
    float* __restrict__ Cf, unsigned short* __restrict__ Cb,
    int M, int N, int K)
{
    __shared__ unsigned short As[BM * BK];
    __shared__ unsigned short Bs[BN * BK];
    const int bm = blockIdx.x * BM;
    const int bn = blockIdx.y * BN;
    const int tid = threadIdx.x;
    const int wave = tid >> 6, lane = tid & 63;
    const int wm = (wave & 1) * 64, wn = (wave >> 1) * 64;
    const int row16 = lane & 15, quad = lane >> 4;

    f32x4 acc[4][4];
#pragma unroll
    for (int i = 0; i < 4; ++i)
#pragma unroll
        for (int j = 0; j < 4; ++j) acc[i][j] = (f32x4){0.f, 0.f, 0.f, 0.f};

    for (int k0 = 0; k0 < K; k0 += BK) {
        __syncthreads();
#pragma unroll
        for (int s = 0; s < 2; ++s) {
            int c = tid + s * 256;
            int r = c >> 2, col = (c & 3) * 8;
            *(uint4*)&As[r * BK + col] = *(const uint4*)&A[(size_t)(bm + r) * K + k0 + col];
            *(uint4*)&Bs[r * BK + col] = *(const uint4*)&B[(size_t)(bn + r) * K + k0 + col];
        }
        __syncthreads();
        bf16x8 af[4], bfr[4];
#pragma unroll
        for (int i = 0; i < 4; ++i) {
            af[i]  = *(const bf16x8*)&As[(wm + i * 16 + row16) * BK + quad * 8];
            bfr[i] = *(const bf16x8*)&Bs[(wn + i * 16 + row16) * BK + quad * 8];
        }
#pragma unroll
        for (int i = 0; i < 4; ++i)
#pragma unroll
            for (int j = 0; j < 4; ++j)
                acc[i][j] = __builtin_amdgcn_mfma_f32_16x16x32_bf16(af[i], bfr[j], acc[i][j], 0, 0, 0);
    }

#pragma unroll
    for (int j = 0; j < 4; ++j) {
        int col = bn + wn + j * 16 + row16;
        float bsum = (bias1 ? bias1[col] : 0.f) + (bias2 ? bias2[col] : 0.f);
#pragma unroll
        for (int i = 0; i < 4; ++i) {
#pragma unroll
            for (int r = 0; r < 4; ++r) {
                int row = bm + wm + i * 16 + quad * 4 + r;
                float v = acc[i][j][r] + bsum;
                if (Cf) Cf[(size_t)row * N + col] = v;
                else    Cb[(size_t)row * N + col] = f2bf(v);
            }
        }
    }
}

// ---------------- persistent LSTM recurrence ----------------
// 256 blocks x 1024 threads, 1 block/CU (LDS 146KB). Block b owns h[b*8..b*8+8)
// and the 32 gate rows {q*2048 + b*8 + j}. W_hh in LDS as bf16 for all steps.
// Cross-block h exchange: self-validating 8B words (tag<<32 | f32bits) in LLC via
// relaxed agent-scope atomics. NO fences, NO L2 inv/wb per step.
#define SW 2056            // Wl row stride (ushorts): 2048 + 8 pad (bank stagger)
#define LSTM_LDS (32 * SW * 2 + 3072 * 4 + 512 * 4 + 32 * 4 + 32 * 4)
__global__ __launch_bounds__(1024, 1) void k_lstm(
    const float* __restrict__ W_hh,          // [8192,2048] fp32
    const unsigned short* __restrict__ xg,   // [4096,8192] bf16
    const float* __restrict__ h0, const float* __restrict__ c0,
    unsigned short* __restrict__ hsb,        // [4096,2048] bf16
    float* __restrict__ outHC,               // d_out + SEQ*NL : [hL(2048), cL(2048)]
    unsigned long long* __restrict__ hcomm)  // [2][2048] tagged h words
{
    extern __shared__ char smem[];
    unsigned short* Wl = (unsigned short*)smem;            // 32 x SW bf16
    float* hl   = (float*)(smem + 32 * SW * 2);            // 256 groups x 12 (8 data + 4 pad)
    float* LDSp = hl + 3072;                               // partials [row][wave] = [32][16]
    float* gsum = LDSp + 512;                              // 32
    float* gxg  = gsum + 32;                               // 32

    const int b = blockIdx.x, tid = threadIdx.x;
    const int wave = tid >> 6, lane = tid & 63;
    const int sub = lane & 15, grp = lane >> 4;

    // stage this block's 32 W_hh rows into LDS as bf16 (local row r = q*8+j)
    for (int i = tid; i < 32 * 2048 / 4; i += 1024) {
        int r = i >> 9;
        int cc = (i & 511) << 2;
        int grow = ((r >> 3) << 11) + b * 8 + (r & 7);
        float4 v = *(const float4*)&W_hh[(size_t)grow * 2048 + cc];
        ushort4 u;
        u.x = f2bf(v.x); u.y = f2bf(v.y); u.z = f2bf(v.z); u.w = f2bf(v.w);
        *(ushort4*)&Wl[r * SW + cc] = u;
    }
    float creg = 0.f;
    if (tid < 8) creg = c0[b * 8 + tid];

    // matvec geometry: wave handles h-cols [wave*128, wave*128+128)
    const int cbase = wave * 128 + sub * 8;       // unpadded col of this lane's 8-chunk
    const int hpad  = (cbase >> 3) * 12;          // padded hl index of that chunk

    __syncthreads();

    for (int t = 0; t < SEQ; ++t) {
        // xg prefetch (overlaps the poll)
        float xgv = 0.f;
        if (tid < 32) {
            int grow = ((tid >> 3) << 11) + b * 8 + (tid & 7);
            xgv = bf2f(xg[(size_t)t * G4 + grow]);
        }

        // fill hl (padded layout: 8 floats + 4 pad per group)
        if (t == 0) {
            for (int i = tid; i < 512; i += 1024) {
                int c = i * 4;
                *(float4*)&hl[(c >> 3) * 12 + (c & 7)] = *(const float4*)&h0[c];
            }
        } else {
            const unsigned long long* src = hcomm + (size_t)((t - 1) & 1) * 2048;
            const int c = tid * 2;
            const unsigned tag = (unsigned)t;
            bool d0 = false, d1 = false;
            float v0 = 0.f, v1 = 0.f;
            for (;;) {
                if (!d0) {
                    unsigned long long x = __hip_atomic_load(&src[c], __ATOMIC_RELAXED,
                                                             __HIP_MEMORY_SCOPE_AGENT);
                    if ((unsigned)(x >> 32) == tag) { v0 = __builtin_bit_cast(float, (unsigned)x); d0 = true; }
                }
                if (!d1) {
                    unsigned long long x = __hip_atomic_load(&src[c + 1], __ATOMIC_RELAXED,
                                                             __HIP_MEMORY_SCOPE_AGENT);
                    if ((unsigned)(x >> 32) == tag) { v1 = __builtin_bit_cast(float, (unsigned)x); d1 = true; }
                }
                if (d0 && d1) break;
                __builtin_amdgcn_s_sleep(1);
            }
            *(float2*)&hl[(c >> 3) * 12 + (c & 7)] = make_float2(v0, v1);
        }
        if (tid < 32) gxg[tid] = xgv;
        __syncthreads();

        // matvec: W read exactly once; h slice in 8 regs/lane
        float4 ha = *(const float4*)&hl[hpad];
        float4 hb = *(const float4*)&hl[hpad + 4];
#pragma unroll
        for (int it = 0; it < 8; ++it) {
            int r = it * 4 + grp;
            uint4 wv = *(const uint4*)&Wl[r * SW + cbase];
            float s = lo16(wv.x) * ha.x + hi16(wv.x) * ha.y
                    + lo16(wv.y) * ha.z + hi16(wv.y) * ha.w
                    + lo16(wv.z) * hb.x + hi16(wv.z) * hb.y
                    + lo16(wv.w) * hb.z + hi16(wv.w) * hb.w;
            s += __shfl_xor(s, 1); s += __shfl_xor(s, 2);
            s += __shfl_xor(s, 4); s += __shfl_xor(s, 8);
            if (sub == 0) LDSp[r * 16 + wave] = s;
        }
        __syncthreads();

        // reduce 16 wave-partials per row
        if (tid < 512) {
            float v = LDSp[tid];
            v += __shfl_xor(v, 1); v += __shfl_xor(v, 2);
            v += __shfl_xor(v, 4); v += __shfl_xor(v, 8);
            if ((tid & 15) == 0) gsum[tid >> 4] = v;
        }
        __syncthreads();

        if (tid < 8) {
            float gi = gsum[tid]      + gxg[tid];
            float gf = gsum[8 + tid]  + gxg[8 + tid];
            float gg = gsum[16 + tid] + gxg[16 + tid];
            float go = gsum[24 + tid] + gxg[24 + tid];
            float i_ = 1.f / (1.f + __expf(-gi));
            float f_ = 1.f / (1.f + __expf(-gf));
            float g_ = tanhf(gg);
            float o_ = 1.f / (1.f + __expf(-go));
            float cn = f_ * creg + i_ * g_;
            float hn = o_ * tanhf(cn);
            creg = cn;
            unsigned fb = __builtin_bit_cast(unsigned, hn);
            __hip_atomic_store(&hcomm[(size_t)(t & 1) * 2048 + b * 8 + tid],
                               (((unsigned long long)(unsigned)(t + 1)) << 32) | fb,
                               __ATOMIC_RELAXED, __HIP_MEMORY_SCOPE_AGENT);
            hsb[(size_t)t * HID + b * 8 + tid] = f2bf(hn);
            if (t == SEQ - 1) {
                outHC[b * 8 + tid] = hn;
                outHC[HID + b * 8 + tid] = cn;
            }
        }
        // next iteration's phase-1 sync orders all remaining hazards
    }
}

// ---------------- relu + log_softmax over rows of 256 ----------------
__global__ __launch_bounds__(256) void k_softmax(const float* __restrict__ logits,
                                                 float* __restrict__ out) {
    int row = blockIdx.x * 4 + (threadIdx.x >> 6);
    int lane = threadIdx.x & 63;
    const float* Lr = logits + (size_t)row * NL;
    float4 v = *(const float4*)&Lr[lane * 4];
    v.x = fmaxf(v.x, 0.f); v.y = fmaxf(v.y, 0.f);
    v.z = fmaxf(v.z, 0.f); v.w = fmaxf(v.w, 0.f);
    float m = fmaxf(fmaxf(v.x, v.y), fmaxf(v.z, v.w));
#pragma unroll
    for (int off = 32; off > 0; off >>= 1) m = fmaxf(m, __shfl_xor(m, off));
    float e = __expf(v.x - m) + __expf(v.y - m) + __expf(v.z - m) + __expf(v.w - m);
#pragma unroll
    for (int off = 32; off > 0; off >>= 1) e += __shfl_xor(e, off);
    float ls = __logf(e) + m;
    float4 o;
    o.x = v.x - ls; o.y = v.y - ls; o.z = v.z - ls; o.w = v.w - ls;
    *(float4*)&out[(size_t)row * NL + lane * 4] = o;
}

extern "C" void kernel_launch(void* const* d_in, const int* in_sizes, int n_in,
                              void* d_out, int out_size, void* d_ws, size_t ws_size,
                              hipStream_t stream) {
    const int*   ids   = (const int*)d_in[0];
    const float* h0    = (const float*)d_in[1];
    const float* c0    = (const float*)d_in[2];
    const float* W_emb = (const float*)d_in[3];
    const float* W_ih  = (const float*)d_in[4];
    const float* W_hh  = (const float*)d_in[5];
    const float* b_ih  = (const float*)d_in[6];
    const float* b_hh  = (const float*)d_in[7];
    const float* W_out = (const float*)d_in[8];
    const float* b_out = (const float*)d_in[9];
    float* out = (float*)d_out;

    char* ws = (char*)d_ws;
    unsigned short* xg    = (unsigned short*)(ws);                 // 64MB  [4096,8192] bf16
    unsigned short* hsb   = (unsigned short*)(ws + 67108864);      // 16MB  [4096,2048] bf16
    unsigned short* Wihb  = (unsigned short*)(ws + 83886080);      // 16MB
    unsigned short* embb  = (unsigned short*)(ws + 100663296);     // 8MB
    unsigned short* Woutb = (unsigned short*)(ws + 109051904);     // 1MB
    float*          logit = (float*)(ws + 110100480);              // 4MB
    unsigned long long* hcomm = (unsigned long long*)(ws + 114294784); // 32KB (poison tag != any step)

    k_f2b<<<(G4 * EMB / 4 + 255) / 256, 256, 0, stream>>>(W_ih, Wihb, G4 * EMB);
    k_f2b<<<(NL * HID / 4 + 255) / 256, 256, 0, stream>>>(W_out, Woutb, NL * HID);
    k_emb<<<SEQ, 256, 0, stream>>>(ids, W_emb, embb);

    dim3 g1(SEQ / BM, G4 / BN);
    k_gemm_bt<<<g1, 256, 0, stream>>>(embb, Wihb, b_ih, b_hh, nullptr, xg, SEQ, G4, EMB);

    hipFuncSetAttribute((const void*)k_lstm, hipFuncAttributeMaxDynamicSharedMemorySize, LSTM_LDS);
    k_lstm<<<256, 1024, LSTM_LDS, stream>>>(W_hh, xg, h0, c0, hsb, out + (size_t)SEQ * NL, hcomm);

    dim3 g2(SEQ / BM, NL / BN);
    k_gemm_bt<<<g2, 256, 0, stream>>>(hsb, Woutb, b_out, nullptr, logit, nullptr, SEQ, NL, HID);

    k_softmax<<<SEQ / 4, 256, 0, stream>>>(logit, out);
}

// Round 3
// 11404.287 us; speedup vs baseline: 8.8750x; 1.6731x over previous
//
#include <hip/hip_runtime.h>
#include <hip/hip_bf16.h>

#define SEQ 4096
#define EMB 1024
#define HID 2048
#define G4  8192
#define NL  256

typedef __attribute__((ext_vector_type(8))) short bf16x8;
typedef __attribute__((ext_vector_type(4))) float f32x4;

static __device__ __forceinline__ unsigned short f2bf(float f) {
    unsigned int x = __builtin_bit_cast(unsigned int, f);
    return (unsigned short)((x + 0x7FFFu + ((x >> 16) & 1u)) >> 16);
}
static __device__ __forceinline__ float bf2f(unsigned short u) {
    return __builtin_bit_cast(float, ((unsigned int)u) << 16);
}

// ---------------- fp32 -> bf16 convert ----------------
__global__ __launch_bounds__(256) void k_f2b(const float* __restrict__ in,
                                             unsigned short* __restrict__ out, int n) {
    int i = (blockIdx.x * 256 + threadIdx.x) * 4;
    if (i < n) {
        float4 v = *(const float4*)&in[i];
        ushort4 u;
        u.x = f2bf(v.x); u.y = f2bf(v.y); u.z = f2bf(v.z); u.w = f2bf(v.w);
        *(ushort4*)&out[i] = u;
    }
}

// ---------------- embedding gather + cast ----------------
__global__ __launch_bounds__(256) void k_emb(const int* __restrict__ ids,
                                             const float* __restrict__ W_emb,
                                             unsigned short* __restrict__ out) {
    int t = blockIdx.x;
    int e0 = threadIdx.x * 4;
    const float4 v = *(const float4*)&W_emb[(size_t)ids[t] * EMB + e0];
    ushort4 u;
    u.x = f2bf(v.x); u.y = f2bf(v.y); u.z = f2bf(v.z); u.w = f2bf(v.w);
    *(ushort4*)&out[(size_t)t * EMB + e0] = u;
}

// ---------------- bf16 MFMA GEMM:  C[M,N] = A[M,K] * B[N,K]^T + bias ----------------
#define BM 128
#define BN 128
#define BK 32
__global__ __launch_bounds__(256) void k_gemm_bt(
    const unsigned short* __restrict__ A, const unsigned short* __restrict__ B,
    const float* __restrict__ bias1, const float* __restrict__ bias2,
    float* __restrict__ Cf, unsigned short* __restrict__ Cb,
    int M, int N, int K)
{
    __shared__ unsigned short As[BM * BK];
    __shared__ unsigned short Bs[BN * BK];
    const int bm = blockIdx.x * BM;
    const int bn = blockIdx.y * BN;
    const int tid = threadIdx.x;
    const int wave = tid >> 6, lane = tid & 63;
    const int wm = (wave & 1) * 64, wn = (wave >> 1) * 64;
    const int row16 = lane & 15, quad = lane >> 4;

    f32x4 acc[4][4];
#pragma unroll
    for (int i = 0; i < 4; ++i)
#pragma unroll
        for (int j = 0; j < 4; ++j) acc[i][j] = (f32x4){0.f, 0.f, 0.f, 0.f};

    for (int k0 = 0; k0 < K; k0 += BK) {
        __syncthreads();
#pragma unroll
        for (int s = 0; s < 2; ++s) {
            int c = tid + s * 256;
            int r = c >> 2, col = (c & 3) * 8;
            *(uint4*)&As[r * BK + col] = *(const uint4*)&A[(size_t)(bm + r) * K + k0 + col];
            *(uint4*)&Bs[r * BK + col] = *(const uint4*)&B[(size_t)(bn + r) * K + k0 + col];
        }
        __syncthreads();
        bf16x8 af[4], bfr[4];
#pragma unroll
        for (int i = 0; i < 4; ++i) {
            af[i]  = *(const bf16x8*)&As[(wm + i * 16 + row16) * BK + quad * 8];
            bfr[i] = *(const bf16x8*)&Bs[(wn + i * 16 + row16) * BK + quad * 8];
        }
#pragma unroll
        for (int i = 0; i < 4; ++i)
#pragma unroll
            for (int j = 0; j < 4; ++j)
                acc[i][j] = __builtin_amdgcn_mfma_f32_16x16x32_bf16(af[i], bfr[j], acc[i][j], 0, 0, 0);
    }

#pragma unroll
    for (int j = 0; j < 4; ++j) {
        int col = bn + wn + j * 16 + row16;
        float bsum = (bias1 ? bias1[col] : 0.f) + (bias2 ? bias2[col] : 0.f);
#pragma unroll
        for (int i = 0; i < 4; ++i) {
#pragma unroll
            for (int r = 0; r < 4; ++r) {
                int row = bm + wm + i * 16 + quad * 4 + r;
                float v = acc[i][j][r] + bsum;
                if (Cf) Cf[(size_t)row * N + col] = v;
                else    Cb[(size_t)row * N + col] = f2bf(v);
            }
        }
    }
}

// ---------------- persistent LSTM recurrence (MFMA, W in registers) ----------------
// 256 blocks x 1024 threads, 1 block/CU (88KB LDS forces it). Block b owns
// h[b*8..b*8+8) and gate rows {q*2048 + b*8 + j}. The 32x2048 W slice lives as
// 8 permanent MFMA A-fragments per lane (32 VGPRs). Per step: poll 1024 tagged
// 8B words (tag32 | 2xbf16) from LLC, build broadcast B-frags from LDS h,
// 8 MFMAs/wave, cross-wave reduce, activation, publish.
#define LSTM_LDS 90112
__global__ __launch_bounds__(1024, 1) void k_lstm(
    const unsigned short* __restrict__ Whhb, // [8192,2048] bf16
    const unsigned short* __restrict__ xg,   // [4096,8192] bf16
    const float* __restrict__ h0, const float* __restrict__ c0,
    unsigned short* __restrict__ hsb,        // [4096,2048] bf16
    float* __restrict__ outHC,               // d_out + SEQ*NL : [hL(2048), cL(2048)]
    unsigned long long* __restrict__ hcomm)  // [2][1024] tagged h word-pairs
{
    extern __shared__ char smem[];
    unsigned short* hl = (unsigned short*)smem;        // 2048 bf16 (4KB)
    unsigned int*  hl32 = (unsigned int*)smem;         // same, as 1024 words
    float* LDSp = (float*)(smem + 4096);               // [32 rows][8 ksets]
    float* gsum = (float*)(smem + 4096 + 1024);        // 32

    const int b = blockIdx.x, tid = threadIdx.x;
    const int wave = tid >> 6, lane = tid & 63;
    const int sub = lane & 15, quad = lane >> 4;
    const int rg = wave & 1, kset = wave >> 1;

    // one-time: load this lane's 8 A-fragments (W rows rg*16+sub, k-chunks kset*8+i)
    const int q = rg * 2 + (sub >> 3);
    const int j = sub & 7;
    const unsigned short* wsrc =
        Whhb + ((size_t)(q * HID + b * 8 + j)) * HID + kset * 8 * 32 + quad * 8;
    bf16x8 afr[8];
#pragma unroll
    for (int i = 0; i < 8; ++i)
        afr[i] = *(const bf16x8*)(wsrc + i * 32);

    float creg = 0.f;
    if (tid < 8) creg = c0[b * 8 + tid];

    for (int t = 0; t < SEQ; ++t) {
        // activation threads prefetch their own 4 x-gate values (hides IF latency)
        float xq0 = 0.f, xq1 = 0.f, xq2 = 0.f, xq3 = 0.f;
        if (tid < 8) {
            const unsigned short* xr = xg + (size_t)t * G4 + b * 8 + tid;
            xq0 = bf2f(xr[0]);
            xq1 = bf2f(xr[2048]);
            xq2 = bf2f(xr[4096]);
            xq3 = bf2f(xr[6144]);
        }

        // fill hl with h_{t-1} (bf16)
        if (t == 0) {
            if (tid < 512) {
                float4 v = *(const float4*)&h0[tid * 4];
                ushort4 u;
                u.x = f2bf(v.x); u.y = f2bf(v.y); u.z = f2bf(v.z); u.w = f2bf(v.w);
                *(ushort4*)&hl[tid * 4] = u;
            }
        } else {
            const unsigned long long* src = hcomm + (size_t)((t - 1) & 1) * 1024;
            const unsigned tag = (unsigned)t;
            unsigned long long x;
            for (;;) {
                x = __hip_atomic_load(&src[tid], __ATOMIC_RELAXED, __HIP_MEMORY_SCOPE_AGENT);
                if ((unsigned)(x >> 32) == tag) break;
                __builtin_amdgcn_s_sleep(1);
            }
            hl32[tid] = (unsigned int)x;
        }
        __syncthreads();   // A: hl complete

        // 8 broadcast B-frags + 8 MFMAs (2 chains for pipelining)
        f32x4 acc0 = (f32x4){0.f, 0.f, 0.f, 0.f};
        f32x4 acc1 = (f32x4){0.f, 0.f, 0.f, 0.f};
#pragma unroll
        for (int i = 0; i < 8; i += 2) {
            bf16x8 h0f = *(const bf16x8*)&hl[(kset * 8 + i) * 32 + quad * 8];
            bf16x8 h1f = *(const bf16x8*)&hl[(kset * 8 + i + 1) * 32 + quad * 8];
            acc0 = __builtin_amdgcn_mfma_f32_16x16x32_bf16(afr[i],     h0f, acc0, 0, 0, 0);
            acc1 = __builtin_amdgcn_mfma_f32_16x16x32_bf16(afr[i + 1], h1f, acc1, 0, 0, 0);
        }
        f32x4 acc = acc0 + acc1;
        // C col 0 (n=0) lives in sub==0 lanes: rows quad*4+reg of rowgroup rg
        if (sub == 0) {
#pragma unroll
            for (int r = 0; r < 4; ++r)
                LDSp[(rg * 16 + quad * 4 + r) * 8 + kset] = acc[r];
        }
        __syncthreads();   // B: partials complete

        // reduce 8 ksets per row
        if (tid < 256) {
            float v = LDSp[tid];
            v += __shfl_xor(v, 1); v += __shfl_xor(v, 2); v += __shfl_xor(v, 4);
            if ((tid & 7) == 0) gsum[tid >> 3] = v;
        }
        __syncthreads();   // C: gsum ready

        if (tid < 8) {
            float gi = gsum[tid]      + xq0;
            float gf = gsum[8 + tid]  + xq1;
            float gg = gsum[16 + tid] + xq2;
            float go = gsum[24 + tid] + xq3;
            float i_ = 1.f / (1.f + __expf(-gi));
            float f_ = 1.f / (1.f + __expf(-gf));
            float g_ = tanhf(gg);
            float o_ = 1.f / (1.f + __expf(-go));
            float cn = f_ * creg + i_ * g_;
            float hn = o_ * tanhf(cn);
            creg = cn;
            unsigned hv = (unsigned)f2bf(hn);
            unsigned ov = (unsigned)__shfl_xor((int)hv, 1);
            if ((tid & 1) == 0) {
                unsigned data = hv | (ov << 16);
                __hip_atomic_store(&hcomm[(size_t)(t & 1) * 1024 + b * 4 + (tid >> 1)],
                                   (((unsigned long long)(unsigned)(t + 1)) << 32) | data,
                                   __ATOMIC_RELAXED, __HIP_MEMORY_SCOPE_AGENT);
            }
            hsb[(size_t)t * HID + b * 8 + tid] = f2bf(hn);
            if (t == SEQ - 1) {
                outHC[b * 8 + tid] = hn;
                outHC[HID + b * 8 + tid] = cn;
            }
        }
        // next step's barrier A orders the remaining LDS hazards
    }
}

// ---------------- relu + log_softmax over rows of 256 ----------------
__global__ __launch_bounds__(256) void k_softmax(const float* __restrict__ logits,
                                                 float* __restrict__ out) {
    int row = blockIdx.x * 4 + (threadIdx.x >> 6);
    int lane = threadIdx.x & 63;
    const float* Lr = logits + (size_t)row * NL;
    float4 v = *(const float4*)&Lr[lane * 4];
    v.x = fmaxf(v.x, 0.f); v.y = fmaxf(v.y, 0.f);
    v.z = fmaxf(v.z, 0.f); v.w = fmaxf(v.w, 0.f);
    float m = fmaxf(fmaxf(v.x, v.y), fmaxf(v.z, v.w));
#pragma unroll
    for (int off = 32; off > 0; off >>= 1) m = fmaxf(m, __shfl_xor(m, off));
    float e = __expf(v.x - m) + __expf(v.y - m) + __expf(v.z - m) + __expf(v.w - m);
#pragma unroll
    for (int off = 32; off > 0; off >>= 1) e += __shfl_xor(e, off);
    float ls = __logf(e) + m;
    float4 o;
    o.x = v.x - ls; o.y = v.y - ls; o.z = v.z - ls; o.w = v.w - ls;
    *(float4*)&out[(size_t)row * NL + lane * 4] = o;
}

extern "C" void kernel_launch(void* const* d_in, const int* in_sizes, int n_in,
                              void* d_out, int out_size, void* d_ws, size_t ws_size,
                              hipStream_t stream) {
    const int*   ids   = (const int*)d_in[0];
    const float* h0    = (const float*)d_in[1];
    const float* c0    = (const float*)d_in[2];
    const float* W_emb = (const float*)d_in[3];
    const float* W_ih  = (const float*)d_in[4];
    const float* W_hh  = (const float*)d_in[5];
    const float* b_ih  = (const float*)d_in[6];
    const float* b_hh  = (const float*)d_in[7];
    const float* W_out = (const float*)d_in[8];
    const float* b_out = (const float*)d_in[9];
    float* out = (float*)d_out;

    char* ws = (char*)d_ws;
    unsigned short* xg    = (unsigned short*)(ws);                 // 64MB  [4096,8192] bf16
    unsigned short* hsb   = (unsigned short*)(ws + 67108864);      // 16MB  [4096,2048] bf16
    unsigned short* Wihb  = (unsigned short*)(ws + 83886080);      // 16MB
    unsigned short* embb  = (unsigned short*)(ws + 100663296);     // 8MB
    unsigned short* Woutb = (unsigned short*)(ws + 109051904);     // 1MB
    float*          logit = (float*)(ws + 110100480);              // 4MB
    unsigned short* Whhb  = (unsigned short*)(ws + 114294784);     // 32MB [8192,2048] bf16
    unsigned long long* hcomm = (unsigned long long*)(ws + 147849216); // 16KB (0xAA poison != any tag)

    k_f2b<<<(G4 * EMB / 4 + 255) / 256, 256, 0, stream>>>(W_ih, Wihb, G4 * EMB);
    k_f2b<<<(NL * HID / 4 + 255) / 256, 256, 0, stream>>>(W_out, Woutb, NL * HID);
    k_f2b<<<(G4 * HID / 4 + 255) / 256, 256, 0, stream>>>(W_hh, Whhb, G4 * HID);
    k_emb<<<SEQ, 256, 0, stream>>>(ids, W_emb, embb);

    dim3 g1(SEQ / BM, G4 / BN);
    k_gemm_bt<<<g1, 256, 0, stream>>>(embb, Wihb, b_ih, b_hh, nullptr, xg, SEQ, G4, EMB);

    hipFuncSetAttribute((const void*)k_lstm, hipFuncAttributeMaxDynamicSharedMemorySize, LSTM_LDS);
    k_lstm<<<256, 1024, LSTM_LDS, stream>>>(Whhb, xg, h0, c0, hsb, out + (size_t)SEQ * NL, hcomm);

    dim3 g2(SEQ / BM, NL / BN);
    k_gemm_bt<<<g2, 256, 0, stream>>>(hsb, Woutb, b_out, nullptr, logit, nullptr, SEQ, NL, HID);

    k_softmax<<<SEQ / 4, 256, 0, stream>>>(logit, out);
}